// Round 11
// baseline (213.822 us; speedup 1.0000x reference)
//
#include <hip/hip_runtime.h>
#include <hip/hip_fp16.h>

#define NHEAD 8
#define NQ 300
#define NBS 32
#define VTOT 8500
#define CDIM 256
#define TQ 16
#define NQT 19  // ceil(300/16)
#define NBLK (NBS * NHEAD * NQT)  // 4864 = 8 XCDs x 608

typedef unsigned int u32x4 __attribute__((ext_vector_type(4)));

// ======= K1: value fp32 [b][idx][256] -> fp16 head-major [(b*8+h)*VTOT+idx][32] =======
// Output-major mapping: writes fully linear. Plain (cached) stores so vh is RETAINED
// in L2/Infinity-Cache for the gather kernel -- nt stores forced cold HBM misses.
__global__ __launch_bounds__(256)
void cvt_kernel(const float* __restrict__ in, __half* __restrict__ o) {
    const int TOT = NBS * NHEAD * VTOT * 4;   // 16B-output chunks = 8,704,000
    int gid = blockIdx.x * 256 + threadIdx.x;
    int stride = gridDim.x * 256;
    for (int t = gid; t < TOT; t += stride) {
        int cq  = t & 3;
        int r   = t >> 2;          // bh*VTOT + idx
        int idx = r % VTOT;
        int bh  = r / VTOT;
        int b   = bh >> 3;
        int h   = bh & 7;
        const float* src = in + (size_t)(b * VTOT + idx) * CDIM + h * 32 + cq * 8;
        float4 f0 = *reinterpret_cast<const float4*>(src);
        float4 f1 = *reinterpret_cast<const float4*>(src + 4);
        __half2 pk[4];
        pk[0] = __halves2half2(__float2half(f0.x), __float2half(f0.y));
        pk[1] = __halves2half2(__float2half(f0.z), __float2half(f0.w));
        pk[2] = __halves2half2(__float2half(f1.x), __float2half(f1.y));
        pk[3] = __halves2half2(__float2half(f1.z), __float2half(f1.w));
        *reinterpret_cast<u32x4*>(o + (size_t)r * 32 + cq * 8) =
            *reinterpret_cast<u32x4*>(pk);
    }
}

// ======= K2: fused GEMM + softmax + paired-corner gather (head-major fp16) =======
__global__ __launch_bounds__(256, 4)
void msda_kernel_f16(const float* __restrict__ query,
                     const float* __restrict__ refp,
                     const __half* __restrict__ vh,
                     const float* __restrict__ W_off,
                     const float* __restrict__ b_off,
                     const float* __restrict__ W_attn,
                     const float* __restrict__ b_attn,
                     float* __restrict__ out) {
    __shared__ float Aq[TQ * 260];        // aliased by Pid2/Pw after phase 1
    __shared__ float S[TQ * 49];
    __shared__ float Rp[TQ * 4];

    int2*   Pid2 = reinterpret_cast<int2*>(Aq);           // 256 int2  = 2048 B
    float4* Pw   = reinterpret_cast<float4*>(Aq + 512);   // 256 float4 = 4096 B

    const int tid = threadIdx.x;
    // Chunked XCD swizzle: pid%8 = XCD -> contiguous b-major chunk per XCD.
    const int pid = blockIdx.x;
    const int bid = (pid & 7) * (NBLK / 8) + (pid >> 3);
    const int b   = bid / (NHEAD * NQT);
    const int r_  = bid - b * (NHEAD * NQT);
    const int h   = r_ / NQT;
    const int qt  = r_ - h * NQT;
    const int q0  = qt * TQ;

    // ---- phase 0: stage query tile + reference points ----
    #pragma unroll
    for (int i = 0; i < 4; ++i) {
        int f4 = i * 256 + tid;
        int q  = f4 >> 6;
        int kk = (f4 & 63) << 2;
        float4 v = make_float4(0.f, 0.f, 0.f, 0.f);
        if (q0 + q < NQ)
            v = *reinterpret_cast<const float4*>(
                    query + ((size_t)(b * NQ + q0 + q) * CDIM + kk));
        *reinterpret_cast<float4*>(&Aq[q * 260 + kk]) = v;
    }
    if (tid < TQ * 4) {
        int q = tid >> 2, c = tid & 3;
        Rp[tid] = (q0 + q < NQ) ? refp[((size_t)(b * NQ + q0 + q)) * 4 + c] : 0.5f;
    }
    __syncthreads();

    // ---- phase 1: GEMM 16q x 48 outputs, thread = (q, 4-col group) ----
    if (tid < 192) {
        const int q = tid / 12;
        const int g = tid - q * 12;
        const float* Wp;
        const float* bp;
        int stride, colbase, j;
        if (g < 8) {
            Wp = W_off;  bp = b_off;  stride = 256;
            colbase = h * 32 + 4 * g;  j = 4 * g;
        } else {
            Wp = W_attn; bp = b_attn; stride = 128;
            colbase = h * 16 + 4 * (g - 8); j = 32 + 4 * (g - 8);
        }
        float4 acc = *reinterpret_cast<const float4*>(bp + colbase);
        const float* a    = &Aq[q * 260];
        const float* wrow = Wp + colbase;
        #pragma unroll 2
        for (int k = 0; k < CDIM; k += 4) {
            float4 av = *reinterpret_cast<const float4*>(a + k);
            float4 w0 = *reinterpret_cast<const float4*>(wrow + (size_t)(k + 0) * stride);
            float4 w1 = *reinterpret_cast<const float4*>(wrow + (size_t)(k + 1) * stride);
            float4 w2 = *reinterpret_cast<const float4*>(wrow + (size_t)(k + 2) * stride);
            float4 w3 = *reinterpret_cast<const float4*>(wrow + (size_t)(k + 3) * stride);
            acc.x = fmaf(av.x, w0.x, acc.x); acc.y = fmaf(av.x, w0.y, acc.y);
            acc.z = fmaf(av.x, w0.z, acc.z); acc.w = fmaf(av.x, w0.w, acc.w);
            acc.x = fmaf(av.y, w1.x, acc.x); acc.y = fmaf(av.y, w1.y, acc.y);
            acc.z = fmaf(av.y, w1.z, acc.z); acc.w = fmaf(av.y, w1.w, acc.w);
            acc.x = fmaf(av.z, w2.x, acc.x); acc.y = fmaf(av.z, w2.y, acc.y);
            acc.z = fmaf(av.z, w2.z, acc.z); acc.w = fmaf(av.z, w2.w, acc.w);
            acc.x = fmaf(av.w, w3.x, acc.x); acc.y = fmaf(av.w, w3.y, acc.y);
            acc.z = fmaf(av.w, w3.z, acc.z); acc.w = fmaf(av.w, w3.w, acc.w);
        }
        S[q * 49 + j + 0] = acc.x;
        S[q * 49 + j + 1] = acc.y;
        S[q * 49 + j + 2] = acc.z;
        S[q * 49 + j + 3] = acc.w;
    }
    __syncthreads();

    // ---- phase 2: softmax + location + row-pair indices / slot weights ----
    {
        const int q = tid >> 4;
        const int p = tid & 15;
        const float* Sq = &S[q * 49];

        float m = Sq[32];
        #pragma unroll
        for (int jj = 1; jj < 16; ++jj) m = fmaxf(m, Sq[32 + jj]);
        float ssum = 0.f;
        #pragma unroll
        for (int jj = 0; jj < 16; ++jj) ssum += __expf(Sq[32 + jj] - m);
        float aw = __expf(Sq[32 + p] - m) / ssum;

        float offx = Sq[2 * p], offy = Sq[2 * p + 1];
        float rx = Rp[q * 4 + 0], ry = Rp[q * 4 + 1];
        float rw = Rp[q * 4 + 2], rh = Rp[q * 4 + 3];
        float locx = rx + offx * 0.25f * rw * 0.5f;
        float locy = ry + offy * 0.25f * rh * 0.5f;

        int l  = p >> 2;
        int Wl = 80 >> l;
        int Hl = Wl;
        int base = (l > 0 ? 6400 : 0) + (l > 1 ? 1600 : 0) + (l > 2 ? 400 : 0);

        float x = locx * (float)Wl - 0.5f;
        float y = locy * (float)Hl - 0.5f;
        float x0f = floorf(x), y0f = floorf(y);
        float lx = x - x0f, ly = y - y0f;
        int x0 = (int)x0f, y0 = (int)y0f;
        int x1 = x0 + 1,   y1 = y0 + 1;

        bool vx0 = (x0 >= 0) && (x0 < Wl);
        bool vx1 = (x1 >= 0) && (x1 < Wl);
        bool vy0 = (y0 >= 0) && (y0 < Hl);
        bool vy1 = (y1 >= 0) && (y1 < Hl);
        int cx0 = min(max(x0, 0), Wl - 1), cx1 = min(max(x1, 0), Wl - 1);
        int cy0 = min(max(y0, 0), Hl - 1), cy1 = min(max(y1, 0), Hl - 1);

        float wx0 = 1.f - lx, wy0 = 1.f - ly;
        float w00 = wx0 * wy0 * aw * (float)(vx0 && vy0);
        float w10 = lx  * wy0 * aw * (float)(vx1 && vy0);
        float w01 = wx0 * ly  * aw * (float)(vx0 && vy1);
        float w11 = lx  * ly  * aw * (float)(vx1 && vy1);

        // fold x-corners into a contiguous pair [bx, bx+1] with slot weights
        int bx = min(max(x0, 0), Wl - 2);
        float ws00 = (cx0 == bx     ? w00 : 0.f) + (cx1 == bx     ? w10 : 0.f);
        float ws01 = (cx0 == bx + 1 ? w00 : 0.f) + (cx1 == bx + 1 ? w10 : 0.f);
        float ws10 = (cx0 == bx     ? w01 : 0.f) + (cx1 == bx     ? w11 : 0.f);
        float ws11 = (cx0 == bx + 1 ? w01 : 0.f) + (cx1 == bx + 1 ? w11 : 0.f);

        int s = (p + q) & 15;  // swizzle (matched by phase 3)
        Pid2[q * 16 + s] = make_int2(base + cy0 * Wl + bx, base + cy1 * Wl + bx);
        Pw[q * 16 + s]   = make_float4(ws00, ws01, ws10, ws11);
    }
    __syncthreads();

    // ---- phase 3: paired-corner gather. thread = (q, row r, 16B slot s8) ----
    {
        const int q  = tid >> 4;          // 16 q
        const int u  = tid & 15;
        const int r  = u >> 3;            // row select (y0 / y1)
        const int s8 = u & 7;             // 16B slot within the 128B x-pair
        const ushort* vbase = reinterpret_cast<const ushort*>(vh)
                              + (size_t)(b * NHEAD + h) * VTOT * 32 + s8 * 8;

        float a0 = 0.f, a1 = 0.f, a2 = 0.f, a3 = 0.f;
        float a4 = 0.f, a5 = 0.f, a6 = 0.f, a7 = 0.f;

        #pragma unroll
        for (int p = 0; p < 16; ++p) {
            int sw = (p + q) & 15;
            int2   rr = Pid2[q * 16 + sw];
            float4 wv = Pw[q * 16 + sw];
            int   rbase = r ? rr.y : rr.x;
            float w     = r ? (s8 < 4 ? wv.z : wv.w)
                            : (s8 < 4 ? wv.x : wv.y);
            uint4 d = *reinterpret_cast<const uint4*>(vbase + (size_t)rbase * 32);
            float2 f0 = __half22float2(*reinterpret_cast<__half2*>(&d.x));
            float2 f1 = __half22float2(*reinterpret_cast<__half2*>(&d.y));
            float2 f2 = __half22float2(*reinterpret_cast<__half2*>(&d.z));
            float2 f3 = __half22float2(*reinterpret_cast<__half2*>(&d.w));
            a0 = fmaf(w, f0.x, a0); a1 = fmaf(w, f0.y, a1);
            a2 = fmaf(w, f1.x, a2); a3 = fmaf(w, f1.y, a3);
            a4 = fmaf(w, f2.x, a4); a5 = fmaf(w, f2.y, a5);
            a6 = fmaf(w, f3.x, a6); a7 = fmaf(w, f3.y, a7);
        }

        // reduce over slot (lane bit 2) and row (lane bit 3)
        #pragma unroll
        for (int m = 4; m <= 8; m <<= 1) {
            a0 += __shfl_xor(a0, m, 64); a1 += __shfl_xor(a1, m, 64);
            a2 += __shfl_xor(a2, m, 64); a3 += __shfl_xor(a3, m, 64);
            a4 += __shfl_xor(a4, m, 64); a5 += __shfl_xor(a5, m, 64);
            a6 += __shfl_xor(a6, m, 64); a7 += __shfl_xor(a7, m, 64);
        }

        int qg = q0 + q;
        if (u < 4 && qg < NQ) {           // u == chan-quad
            float* op = out + ((size_t)(b * NQ + qg)) * CDIM + h * 32 + u * 8;
            *reinterpret_cast<float4*>(op)     = make_float4(a0, a1, a2, a3);
            *reinterpret_cast<float4*>(op + 4) = make_float4(a4, a5, a6, a7);
        }
    }
}

// ======= fp32 single-kernel fallback if ws too small =======
__global__ __launch_bounds__(256, 8)
void msda_kernel_f32(const float* __restrict__ query,
                     const float* __restrict__ refp,
                     const float* __restrict__ value,
                     const float* __restrict__ W_off,
                     const float* __restrict__ b_off,
                     const float* __restrict__ W_attn,
                     const float* __restrict__ b_attn,
                     float* __restrict__ out) {
    __shared__ float Aq[TQ * 260];
    __shared__ float S[TQ * 49];
    __shared__ float Rp[TQ * 4];
    float* P = Aq;

    const int tid = threadIdx.x;
    const int bh  = blockIdx.x & 255;
    const int b   = bh >> 3;
    const int h   = bh & 7;
    const int qt  = blockIdx.x >> 8;
    const int q0  = qt * TQ;

    #pragma unroll
    for (int i = 0; i < 4; ++i) {
        int f4 = i * 256 + tid;
        int q  = f4 >> 6;
        int kk = (f4 & 63) << 2;
        float4 v = make_float4(0.f, 0.f, 0.f, 0.f);
        if (q0 + q < NQ)
            v = *reinterpret_cast<const float4*>(
                    query + ((size_t)(b * NQ + q0 + q) * CDIM + kk));
        *reinterpret_cast<float4*>(&Aq[q * 260 + kk]) = v;
    }
    if (tid < TQ * 4) {
        int q = tid >> 2, c = tid & 3;
        Rp[tid] = (q0 + q < NQ) ? refp[((size_t)(b * NQ + q0 + q)) * 4 + c] : 0.5f;
    }
    __syncthreads();

    if (tid < 192) {
        const int q = tid / 12;
        const int g = tid - q * 12;
        const float* Wp; const float* bp;
        int stride, colbase, j;
        if (g < 8) { Wp = W_off;  bp = b_off;  stride = 256; colbase = h * 32 + 4 * g; j = 4 * g; }
        else       { Wp = W_attn; bp = b_attn; stride = 128; colbase = h * 16 + 4 * (g - 8); j = 32 + 4 * (g - 8); }
        float4 acc = *reinterpret_cast<const float4*>(bp + colbase);
        const float* a    = &Aq[q * 260];
        const float* wrow = Wp + colbase;
        for (int k = 0; k < CDIM; k += 4) {
            float4 av = *reinterpret_cast<const float4*>(a + k);
            float4 w0 = *reinterpret_cast<const float4*>(wrow + (size_t)(k + 0) * stride);
            float4 w1 = *reinterpret_cast<const float4*>(wrow + (size_t)(k + 1) * stride);
            float4 w2 = *reinterpret_cast<const float4*>(wrow + (size_t)(k + 2) * stride);
            float4 w3 = *reinterpret_cast<const float4*>(wrow + (size_t)(k + 3) * stride);
            acc.x = fmaf(av.x, w0.x, acc.x); acc.y = fmaf(av.x, w0.y, acc.y);
            acc.z = fmaf(av.x, w0.z, acc.z); acc.w = fmaf(av.x, w0.w, acc.w);
            acc.x = fmaf(av.y, w1.x, acc.x); acc.y = fmaf(av.y, w1.y, acc.y);
            acc.z = fmaf(av.y, w1.z, acc.z); acc.w = fmaf(av.y, w1.w, acc.w);
            acc.x = fmaf(av.z, w2.x, acc.x); acc.y = fmaf(av.z, w2.y, acc.y);
            acc.z = fmaf(av.z, w2.z, acc.z); acc.w = fmaf(av.z, w2.w, acc.w);
            acc.x = fmaf(av.w, w3.x, acc.x); acc.y = fmaf(av.w, w3.y, acc.y);
            acc.z = fmaf(av.w, w3.z, acc.z); acc.w = fmaf(av.w, w3.w, acc.w);
        }
        S[q * 49 + j + 0] = acc.x; S[q * 49 + j + 1] = acc.y;
        S[q * 49 + j + 2] = acc.z; S[q * 49 + j + 3] = acc.w;
    }
    __syncthreads();

    {
        const int q = tid >> 4;
        const int p = tid & 15;
        const float* Sq = &S[q * 49];
        float m = Sq[32];
        #pragma unroll
        for (int jj = 1; jj < 16; ++jj) m = fmaxf(m, Sq[32 + jj]);
        float ssum = 0.f;
        #pragma unroll
        for (int jj = 0; jj < 16; ++jj) ssum += __expf(Sq[32 + jj] - m);
        float aw = __expf(Sq[32 + p] - m) / ssum;

        float offx = Sq[2 * p], offy = Sq[2 * p + 1];
        float rx = Rp[q * 4 + 0], ry = Rp[q * 4 + 1];
        float rw = Rp[q * 4 + 2], rh = Rp[q * 4 + 3];
        float locx = rx + offx * 0.25f * rw * 0.5f;
        float locy = ry + offy * 0.25f * rh * 0.5f;

        int l  = p >> 2;
        int Wl = 80 >> l, Hl = Wl;
        int base = (l > 0 ? 6400 : 0) + (l > 1 ? 1600 : 0) + (l > 2 ? 400 : 0);
        float x = locx * (float)Wl - 0.5f;
        float y = locy * (float)Hl - 0.5f;
        float x0f = floorf(x), y0f = floorf(y);
        float lx = x - x0f, ly = y - y0f;
        int x0 = (int)x0f, y0 = (int)y0f;
        int x1 = x0 + 1,   y1 = y0 + 1;
        bool vx0 = (x0 >= 0) && (x0 < Wl);
        bool vx1 = (x1 >= 0) && (x1 < Wl);
        bool vy0 = (y0 >= 0) && (y0 < Hl);
        bool vy1 = (y1 >= 0) && (y1 < Hl);
        int cx0 = min(max(x0, 0), Wl - 1), cx1 = min(max(x1, 0), Wl - 1);
        int cy0 = min(max(y0, 0), Hl - 1), cy1 = min(max(y1, 0), Hl - 1);
        float wx0 = 1.f - lx, wy0 = 1.f - ly;
        float w00 = wx0 * wy0 * aw * (float)(vx0 && vy0);
        float w10 = lx  * wy0 * aw * (float)(vx1 && vy0);
        float w01 = wx0 * ly  * aw * (float)(vx0 && vy1);
        float w11 = lx  * ly  * aw * (float)(vx1 && vy1);

        float* Pe = &P[(q * 16 + p) * 8];
        Pe[0] = __int_as_float(base + cy0 * Wl + cx0);
        Pe[1] = __int_as_float(base + cy0 * Wl + cx1);
        Pe[2] = __int_as_float(base + cy1 * Wl + cx0);
        Pe[3] = __int_as_float(base + cy1 * Wl + cx1);
        Pe[4] = w00; Pe[5] = w10; Pe[6] = w01; Pe[7] = w11;
    }
    __syncthreads();

    {
        const int qi = tid >> 5;
        const int ch = tid & 31;
        const float* vptr = value + (size_t)b * VTOT * CDIM + h * 32 + ch;
        for (int qq = qi; qq < TQ; qq += 8) {
            float acc = 0.f;
            #pragma unroll
            for (int p = 0; p < 16; ++p) {
                const float* Pe = &P[(qq * 16 + p) * 8];
                int4   id = *reinterpret_cast<const int4*>(Pe);
                float4 w  = *reinterpret_cast<const float4*>(Pe + 4);
                acc = fmaf(w.x, vptr[(size_t)id.x * CDIM], acc);
                acc = fmaf(w.y, vptr[(size_t)id.y * CDIM], acc);
                acc = fmaf(w.z, vptr[(size_t)id.z * CDIM], acc);
                acc = fmaf(w.w, vptr[(size_t)id.w * CDIM], acc);
            }
            int q = q0 + qq;
            if (q < NQ)
                out[((size_t)b * NQ + q) * CDIM + h * 32 + ch] = acc;
        }
    }
}

extern "C" void kernel_launch(void* const* d_in, const int* in_sizes, int n_in,
                              void* d_out, int out_size, void* d_ws, size_t ws_size,
                              hipStream_t stream) {
    const float* query  = (const float*)d_in[0];
    const float* refp   = (const float*)d_in[1];
    const float* value  = (const float*)d_in[2];
    const float* W_off  = (const float*)d_in[3];
    const float* b_off  = (const float*)d_in[4];
    const float* W_attn = (const float*)d_in[5];
    const float* b_attn = (const float*)d_in[6];
    float* out = (float*)d_out;

    const size_t need = (size_t)NBS * VTOT * CDIM * sizeof(__half);  // 139 MB
    if (ws_size >= need) {
        __half* vh = (__half*)d_ws;
        cvt_kernel<<<2048, 256, 0, stream>>>(value, vh);
        msda_kernel_f16<<<NBLK, 256, 0, stream>>>(query, refp, vh, W_off, b_off,
                                                  W_attn, b_attn, out);
    } else {
        msda_kernel_f32<<<NQT * 256, 256, 0, stream>>>(query, refp, value, W_off, b_off,
                                                       W_attn, b_attn, out);
    }
}

// Round 12
// 146.042 us; speedup vs baseline: 1.4641x; 1.4641x over previous
//
#include <hip/hip_runtime.h>

#define NHEAD 8
#define NQ 300
#define NBS 32
#define VTOT 8500
#define CDIM 256
#define TQ 16
#define NQT 19  // ceil(300/16)
#define NBLK (NBS * NHEAD * NQT)  // 4864 = 8 XCDs x 608

// Fully fused MSDA, direct fp32 gather (no cvt pass, no workspace).
__global__ __launch_bounds__(256, 4)
void msda_kernel(const float* __restrict__ query,
                 const float* __restrict__ refp,
                 const float* __restrict__ value,
                 const float* __restrict__ W_off,
                 const float* __restrict__ b_off,
                 const float* __restrict__ W_attn,
                 const float* __restrict__ b_attn,
                 float* __restrict__ out) {
    __shared__ float Aq[TQ * 260];        // aliased by Pid/Pw after phase 1
    __shared__ float S[TQ * 49];
    __shared__ float Rp[TQ * 4];

    int4*   Pid = reinterpret_cast<int4*>(Aq);            // 256 int4  = 4096 B
    float4* Pw  = reinterpret_cast<float4*>(Aq + 1024);   // 256 float4 = 4096 B

    const int tid = threadIdx.x;
    // Chunked XCD swizzle: pid%8 = XCD -> contiguous b-major chunk per XCD.
    const int pid = blockIdx.x;
    const int bid = (pid & 7) * (NBLK / 8) + (pid >> 3);
    const int b   = bid / (NHEAD * NQT);
    const int r_  = bid - b * (NHEAD * NQT);
    const int h   = r_ / NQT;
    const int qt  = r_ - h * NQT;
    const int q0  = qt * TQ;

    // ---- phase 0: stage query tile + reference points ----
    #pragma unroll
    for (int i = 0; i < 4; ++i) {
        int f4 = i * 256 + tid;
        int q  = f4 >> 6;
        int kk = (f4 & 63) << 2;
        float4 v = make_float4(0.f, 0.f, 0.f, 0.f);
        if (q0 + q < NQ)
            v = *reinterpret_cast<const float4*>(
                    query + ((size_t)(b * NQ + q0 + q) * CDIM + kk));
        *reinterpret_cast<float4*>(&Aq[q * 260 + kk]) = v;
    }
    if (tid < TQ * 4) {
        int q = tid >> 2, c = tid & 3;
        Rp[tid] = (q0 + q < NQ) ? refp[((size_t)(b * NQ + q0 + q)) * 4 + c] : 0.5f;
    }
    __syncthreads();

    // ---- phase 1: GEMM 16q x 48 outputs, thread = (q, 4-col group) ----
    if (tid < 192) {
        const int q = tid / 12;
        const int g = tid - q * 12;
        const float* Wp;
        const float* bp;
        int stride, colbase, j;
        if (g < 8) {
            Wp = W_off;  bp = b_off;  stride = 256;
            colbase = h * 32 + 4 * g;  j = 4 * g;
        } else {
            Wp = W_attn; bp = b_attn; stride = 128;
            colbase = h * 16 + 4 * (g - 8); j = 32 + 4 * (g - 8);
        }
        float4 acc = *reinterpret_cast<const float4*>(bp + colbase);
        const float* a    = &Aq[q * 260];
        const float* wrow = Wp + colbase;
        #pragma unroll 2
        for (int k = 0; k < CDIM; k += 4) {
            float4 av = *reinterpret_cast<const float4*>(a + k);
            float4 w0 = *reinterpret_cast<const float4*>(wrow + (size_t)(k + 0) * stride);
            float4 w1 = *reinterpret_cast<const float4*>(wrow + (size_t)(k + 1) * stride);
            float4 w2 = *reinterpret_cast<const float4*>(wrow + (size_t)(k + 2) * stride);
            float4 w3 = *reinterpret_cast<const float4*>(wrow + (size_t)(k + 3) * stride);
            acc.x = fmaf(av.x, w0.x, acc.x); acc.y = fmaf(av.x, w0.y, acc.y);
            acc.z = fmaf(av.x, w0.z, acc.z); acc.w = fmaf(av.x, w0.w, acc.w);
            acc.x = fmaf(av.y, w1.x, acc.x); acc.y = fmaf(av.y, w1.y, acc.y);
            acc.z = fmaf(av.y, w1.z, acc.z); acc.w = fmaf(av.y, w1.w, acc.w);
            acc.x = fmaf(av.z, w2.x, acc.x); acc.y = fmaf(av.z, w2.y, acc.y);
            acc.z = fmaf(av.z, w2.z, acc.z); acc.w = fmaf(av.z, w2.w, acc.w);
            acc.x = fmaf(av.w, w3.x, acc.x); acc.y = fmaf(av.w, w3.y, acc.y);
            acc.z = fmaf(av.w, w3.z, acc.z); acc.w = fmaf(av.w, w3.w, acc.w);
        }
        S[q * 49 + j + 0] = acc.x;
        S[q * 49 + j + 1] = acc.y;
        S[q * 49 + j + 2] = acc.z;
        S[q * 49 + j + 3] = acc.w;
    }
    __syncthreads();

    // ---- phase 2: softmax + location + corner idx / premultiplied weights ----
    {
        const int q = tid >> 4;
        const int p = tid & 15;
        const float* Sq = &S[q * 49];

        float m = Sq[32];
        #pragma unroll
        for (int jj = 1; jj < 16; ++jj) m = fmaxf(m, Sq[32 + jj]);
        float ssum = 0.f;
        #pragma unroll
        for (int jj = 0; jj < 16; ++jj) ssum += __expf(Sq[32 + jj] - m);
        float aw = __expf(Sq[32 + p] - m) / ssum;

        float offx = Sq[2 * p], offy = Sq[2 * p + 1];
        float rx = Rp[q * 4 + 0], ry = Rp[q * 4 + 1];
        float rw = Rp[q * 4 + 2], rh = Rp[q * 4 + 3];
        float locx = rx + offx * 0.25f * rw * 0.5f;
        float locy = ry + offy * 0.25f * rh * 0.5f;

        int l  = p >> 2;
        int Wl = 80 >> l;
        int Hl = Wl;
        int base = (l > 0 ? 6400 : 0) + (l > 1 ? 1600 : 0) + (l > 2 ? 400 : 0);

        float x = locx * (float)Wl - 0.5f;
        float y = locy * (float)Hl - 0.5f;
        float x0f = floorf(x), y0f = floorf(y);
        float lx = x - x0f, ly = y - y0f;
        int x0 = (int)x0f, y0 = (int)y0f;
        int x1 = x0 + 1,   y1 = y0 + 1;

        bool vx0 = (x0 >= 0) && (x0 < Wl);
        bool vx1 = (x1 >= 0) && (x1 < Wl);
        bool vy0 = (y0 >= 0) && (y0 < Hl);
        bool vy1 = (y1 >= 0) && (y1 < Hl);
        int cx0 = min(max(x0, 0), Wl - 1), cx1 = min(max(x1, 0), Wl - 1);
        int cy0 = min(max(y0, 0), Hl - 1), cy1 = min(max(y1, 0), Hl - 1);

        float wx0 = 1.f - lx, wy0 = 1.f - ly;
        float w00 = wx0 * wy0 * aw * (float)(vx0 && vy0);
        float w10 = lx  * wy0 * aw * (float)(vx1 && vy0);
        float w01 = wx0 * ly  * aw * (float)(vx0 && vy1);
        float w11 = lx  * ly  * aw * (float)(vx1 && vy1);

        int s = (p + q) & 15;  // bank swizzle (matched by phase 3)
        Pid[q * 16 + s] = make_int4(base + cy0 * Wl + cx0, base + cy0 * Wl + cx1,
                                    base + cy1 * Wl + cx0, base + cy1 * Wl + cx1);
        Pw[q * 16 + s]  = make_float4(w00, w10, w01, w11);
    }
    __syncthreads();

    // ---- phase 3: fp32 dwordx4 gathers; each corner = one aligned 128B line ----
    {
        const int cp4 = tid & 3;          // 16B quad within the 64B half-slice
        const int ps  = (tid >> 2) & 3;   // 4-way p-split
        const int q   = tid >> 4;         // 16 q
        const float* vbase = value + (size_t)b * VTOT * CDIM + h * 32 + cp4 * 4;

        float a0 = 0.f, a1 = 0.f, a2 = 0.f, a3 = 0.f;   // channels cp4*4 .. +3
        float a4 = 0.f, a5 = 0.f, a6 = 0.f, a7 = 0.f;   // channels 16+cp4*4 ..

        #define ACC4(dv, wv, lo)                                         \
        {                                                                \
            if (lo) {                                                    \
                a0 = fmaf(wv, dv.x, a0); a1 = fmaf(wv, dv.y, a1);        \
                a2 = fmaf(wv, dv.z, a2); a3 = fmaf(wv, dv.w, a3);        \
            } else {                                                     \
                a4 = fmaf(wv, dv.x, a4); a5 = fmaf(wv, dv.y, a5);        \
                a6 = fmaf(wv, dv.z, a6); a7 = fmaf(wv, dv.w, a7);        \
            }                                                            \
        }

        #pragma unroll
        for (int j = 0; j < 4; ++j) {
            int p = ps + 4 * j;
            int s = (p + q) & 15;
            int4   id = Pid[q * 16 + s];
            float4 w  = Pw[q * 16 + s];
            const float* p0 = vbase + (size_t)id.x * CDIM;
            const float* p1 = vbase + (size_t)id.y * CDIM;
            const float* p2 = vbase + (size_t)id.z * CDIM;
            const float* p3 = vbase + (size_t)id.w * CDIM;
            // 8 independent 16B loads in flight per p
            float4 d0l = *reinterpret_cast<const float4*>(p0);
            float4 d0h = *reinterpret_cast<const float4*>(p0 + 16);
            float4 d1l = *reinterpret_cast<const float4*>(p1);
            float4 d1h = *reinterpret_cast<const float4*>(p1 + 16);
            float4 d2l = *reinterpret_cast<const float4*>(p2);
            float4 d2h = *reinterpret_cast<const float4*>(p2 + 16);
            float4 d3l = *reinterpret_cast<const float4*>(p3);
            float4 d3h = *reinterpret_cast<const float4*>(p3 + 16);
            ACC4(d0l, w.x, 1); ACC4(d0h, w.x, 0);
            ACC4(d1l, w.y, 1); ACC4(d1h, w.y, 0);
            ACC4(d2l, w.z, 1); ACC4(d2h, w.z, 0);
            ACC4(d3l, w.w, 1); ACC4(d3h, w.w, 0);
        }
        #undef ACC4

        // reduce over ps (lane bits 2,3)
        #pragma unroll
        for (int m = 4; m <= 8; m <<= 1) {
            a0 += __shfl_xor(a0, m, 64); a1 += __shfl_xor(a1, m, 64);
            a2 += __shfl_xor(a2, m, 64); a3 += __shfl_xor(a3, m, 64);
            a4 += __shfl_xor(a4, m, 64); a5 += __shfl_xor(a5, m, 64);
            a6 += __shfl_xor(a6, m, 64); a7 += __shfl_xor(a7, m, 64);
        }

        int qg = q0 + q;
        if (ps == 0 && qg < NQ) {
            float* op = out + ((size_t)(b * NQ + qg)) * CDIM + h * 32;
            *reinterpret_cast<float4*>(op + cp4 * 4)      = make_float4(a0, a1, a2, a3);
            *reinterpret_cast<float4*>(op + 16 + cp4 * 4) = make_float4(a4, a5, a6, a7);
        }
    }
}

extern "C" void kernel_launch(void* const* d_in, const int* in_sizes, int n_in,
                              void* d_out, int out_size, void* d_ws, size_t ws_size,
                              hipStream_t stream) {
    const float* query  = (const float*)d_in[0];
    const float* refp   = (const float*)d_in[1];
    const float* value  = (const float*)d_in[2];
    const float* W_off  = (const float*)d_in[3];
    const float* b_off  = (const float*)d_in[4];
    const float* W_attn = (const float*)d_in[5];
    const float* b_attn = (const float*)d_in[6];
    float* out = (float*)d_out;

    msda_kernel<<<NBLK, 256, 0, stream>>>(query, refp, value, W_off, b_off,
                                          W_attn, b_attn, out);
}

// Round 13
// 142.319 us; speedup vs baseline: 1.5024x; 1.0262x over previous
//
#include <hip/hip_runtime.h>

#define NHEAD 8
#define NQ 300
#define NBS 32
#define VTOT 8500
#define CDIM 256
#define TQ 16
#define NQT 19  // ceil(300/16)
#define NBLK (NBS * NHEAD * NQT)  // 4864 = 8 XCDs x 608

// Fully fused MSDA, direct fp32 gather, deep-batched loads for MLP.
__global__ __launch_bounds__(256, 2)
void msda_kernel(const float* __restrict__ query,
                 const float* __restrict__ refp,
                 const float* __restrict__ value,
                 const float* __restrict__ W_off,
                 const float* __restrict__ b_off,
                 const float* __restrict__ W_attn,
                 const float* __restrict__ b_attn,
                 float* __restrict__ out) {
    __shared__ float Aq[TQ * 260];        // aliased by Pid/Pw after phase 1
    __shared__ float S[TQ * 49];
    __shared__ float Rp[TQ * 4];

    int4*   Pid = reinterpret_cast<int4*>(Aq);            // 256 int4  = 4096 B
    float4* Pw  = reinterpret_cast<float4*>(Aq + 1024);   // 256 float4 = 4096 B

    const int tid = threadIdx.x;
    // Chunked XCD swizzle: pid%8 = XCD -> contiguous b-major chunk per XCD.
    const int pid = blockIdx.x;
    const int bid = (pid & 7) * (NBLK / 8) + (pid >> 3);
    const int b   = bid / (NHEAD * NQT);
    const int r_  = bid - b * (NHEAD * NQT);
    const int h   = r_ / NQT;
    const int qt  = r_ - h * NQT;
    const int q0  = qt * TQ;

    // ---- phase 0: stage query tile + reference points ----
    #pragma unroll
    for (int i = 0; i < 4; ++i) {
        int f4 = i * 256 + tid;
        int q  = f4 >> 6;
        int kk = (f4 & 63) << 2;
        float4 v = make_float4(0.f, 0.f, 0.f, 0.f);
        if (q0 + q < NQ)
            v = *reinterpret_cast<const float4*>(
                    query + ((size_t)(b * NQ + q0 + q) * CDIM + kk));
        *reinterpret_cast<float4*>(&Aq[q * 260 + kk]) = v;
    }
    if (tid < TQ * 4) {
        int q = tid >> 2, c = tid & 3;
        Rp[tid] = (q0 + q < NQ) ? refp[((size_t)(b * NQ + q0 + q)) * 4 + c] : 0.5f;
    }
    __syncthreads();

    // ---- phase 1: GEMM 16q x 48 outputs, thread = (q, 4-col group) ----
    if (tid < 192) {
        const int q = tid / 12;
        const int g = tid - q * 12;
        const float* Wp;
        const float* bp;
        int stride, colbase, j;
        if (g < 8) {
            Wp = W_off;  bp = b_off;  stride = 256;
            colbase = h * 32 + 4 * g;  j = 4 * g;
        } else {
            Wp = W_attn; bp = b_attn; stride = 128;
            colbase = h * 16 + 4 * (g - 8); j = 32 + 4 * (g - 8);
        }
        float4 acc = *reinterpret_cast<const float4*>(bp + colbase);
        const float* a    = &Aq[q * 260];
        const float* wrow = Wp + colbase;
        #pragma unroll 2
        for (int k = 0; k < CDIM; k += 4) {
            float4 av = *reinterpret_cast<const float4*>(a + k);
            float4 w0 = *reinterpret_cast<const float4*>(wrow + (size_t)(k + 0) * stride);
            float4 w1 = *reinterpret_cast<const float4*>(wrow + (size_t)(k + 1) * stride);
            float4 w2 = *reinterpret_cast<const float4*>(wrow + (size_t)(k + 2) * stride);
            float4 w3 = *reinterpret_cast<const float4*>(wrow + (size_t)(k + 3) * stride);
            acc.x = fmaf(av.x, w0.x, acc.x); acc.y = fmaf(av.x, w0.y, acc.y);
            acc.z = fmaf(av.x, w0.z, acc.z); acc.w = fmaf(av.x, w0.w, acc.w);
            acc.x = fmaf(av.y, w1.x, acc.x); acc.y = fmaf(av.y, w1.y, acc.y);
            acc.z = fmaf(av.y, w1.z, acc.z); acc.w = fmaf(av.y, w1.w, acc.w);
            acc.x = fmaf(av.z, w2.x, acc.x); acc.y = fmaf(av.z, w2.y, acc.y);
            acc.z = fmaf(av.z, w2.z, acc.z); acc.w = fmaf(av.z, w2.w, acc.w);
            acc.x = fmaf(av.w, w3.x, acc.x); acc.y = fmaf(av.w, w3.y, acc.y);
            acc.z = fmaf(av.w, w3.z, acc.z); acc.w = fmaf(av.w, w3.w, acc.w);
        }
        S[q * 49 + j + 0] = acc.x;
        S[q * 49 + j + 1] = acc.y;
        S[q * 49 + j + 2] = acc.z;
        S[q * 49 + j + 3] = acc.w;
    }
    __syncthreads();

    // ---- phase 2: softmax + location + corner idx / premultiplied weights ----
    {
        const int q = tid >> 4;
        const int p = tid & 15;
        const float* Sq = &S[q * 49];

        float m = Sq[32];
        #pragma unroll
        for (int jj = 1; jj < 16; ++jj) m = fmaxf(m, Sq[32 + jj]);
        float ssum = 0.f;
        #pragma unroll
        for (int jj = 0; jj < 16; ++jj) ssum += __expf(Sq[32 + jj] - m);
        float aw = __expf(Sq[32 + p] - m) / ssum;

        float offx = Sq[2 * p], offy = Sq[2 * p + 1];
        float rx = Rp[q * 4 + 0], ry = Rp[q * 4 + 1];
        float rw = Rp[q * 4 + 2], rh = Rp[q * 4 + 3];
        float locx = rx + offx * 0.25f * rw * 0.5f;
        float locy = ry + offy * 0.25f * rh * 0.5f;

        int l  = p >> 2;
        int Wl = 80 >> l;
        int Hl = Wl;
        int base = (l > 0 ? 6400 : 0) + (l > 1 ? 1600 : 0) + (l > 2 ? 400 : 0);

        float x = locx * (float)Wl - 0.5f;
        float y = locy * (float)Hl - 0.5f;
        float x0f = floorf(x), y0f = floorf(y);
        float lx = x - x0f, ly = y - y0f;
        int x0 = (int)x0f, y0 = (int)y0f;
        int x1 = x0 + 1,   y1 = y0 + 1;

        bool vx0 = (x0 >= 0) && (x0 < Wl);
        bool vx1 = (x1 >= 0) && (x1 < Wl);
        bool vy0 = (y0 >= 0) && (y0 < Hl);
        bool vy1 = (y1 >= 0) && (y1 < Hl);
        int cx0 = min(max(x0, 0), Wl - 1), cx1 = min(max(x1, 0), Wl - 1);
        int cy0 = min(max(y0, 0), Hl - 1), cy1 = min(max(y1, 0), Hl - 1);

        float wx0 = 1.f - lx, wy0 = 1.f - ly;
        float w00 = wx0 * wy0 * aw * (float)(vx0 && vy0);
        float w10 = lx  * wy0 * aw * (float)(vx1 && vy0);
        float w01 = wx0 * ly  * aw * (float)(vx0 && vy1);
        float w11 = lx  * ly  * aw * (float)(vx1 && vy1);

        int s = (p + q) & 15;  // bank swizzle (matched by phase 3)
        Pid[q * 16 + s] = make_int4(base + cy0 * Wl + cx0, base + cy0 * Wl + cx1,
                                    base + cy1 * Wl + cx0, base + cy1 * Wl + cx1);
        Pw[q * 16 + s]  = make_float4(w00, w10, w01, w11);
    }
    __syncthreads();

    // ---- phase 3: fp32 gathers, 16-deep load batches for MLP ----
    {
        const int cp4 = tid & 3;          // 16B quad within the 64B half-slice
        const int ps  = (tid >> 2) & 3;   // 4-way p-split
        const int q   = tid >> 4;         // 16 q
        const float* vbase = value + (size_t)b * VTOT * CDIM + h * 32 + cp4 * 4;

        // preload P entries for this thread's 4 p's
        int4   id0, id1, id2, id3;
        float4 w0, w1, w2, w3;
        { int s = (ps + 0  + q) & 15; id0 = Pid[q * 16 + s]; w0 = Pw[q * 16 + s]; }
        { int s = (ps + 4  + q) & 15; id1 = Pid[q * 16 + s]; w1 = Pw[q * 16 + s]; }
        { int s = (ps + 8  + q) & 15; id2 = Pid[q * 16 + s]; w2 = Pw[q * 16 + s]; }
        { int s = (ps + 12 + q) & 15; id3 = Pid[q * 16 + s]; w3 = Pw[q * 16 + s]; }

        const float* c00 = vbase + (size_t)id0.x * CDIM;
        const float* c01 = vbase + (size_t)id0.y * CDIM;
        const float* c02 = vbase + (size_t)id0.z * CDIM;
        const float* c03 = vbase + (size_t)id0.w * CDIM;
        const float* c10 = vbase + (size_t)id1.x * CDIM;
        const float* c11 = vbase + (size_t)id1.y * CDIM;
        const float* c12 = vbase + (size_t)id1.z * CDIM;
        const float* c13 = vbase + (size_t)id1.w * CDIM;
        const float* c20 = vbase + (size_t)id2.x * CDIM;
        const float* c21 = vbase + (size_t)id2.y * CDIM;
        const float* c22 = vbase + (size_t)id2.z * CDIM;
        const float* c23 = vbase + (size_t)id2.w * CDIM;
        const float* c30 = vbase + (size_t)id3.x * CDIM;
        const float* c31 = vbase + (size_t)id3.y * CDIM;
        const float* c32 = vbase + (size_t)id3.z * CDIM;
        const float* c33 = vbase + (size_t)id3.w * CDIM;

        float a0 = 0.f, a1 = 0.f, a2 = 0.f, a3 = 0.f;   // channels cp4*4 ..
        float a4 = 0.f, a5 = 0.f, a6 = 0.f, a7 = 0.f;   // channels 16+cp4*4 ..

        #define LD(p) (*reinterpret_cast<const float4*>(p))
        #define ACCL(dv, wv) { a0 = fmaf(wv, dv.x, a0); a1 = fmaf(wv, dv.y, a1); \
                               a2 = fmaf(wv, dv.z, a2); a3 = fmaf(wv, dv.w, a3); }
        #define ACCH(dv, wv) { a4 = fmaf(wv, dv.x, a4); a5 = fmaf(wv, dv.y, a5); \
                               a6 = fmaf(wv, dv.z, a6); a7 = fmaf(wv, dv.w, a7); }

        // batch 1: 16 independent lo-half loads in flight
        {
            float4 d00 = LD(c00), d01 = LD(c01), d02 = LD(c02), d03 = LD(c03);
            float4 d10 = LD(c10), d11 = LD(c11), d12 = LD(c12), d13 = LD(c13);
            float4 d20 = LD(c20), d21 = LD(c21), d22 = LD(c22), d23 = LD(c23);
            float4 d30 = LD(c30), d31 = LD(c31), d32 = LD(c32), d33 = LD(c33);
            ACCL(d00, w0.x); ACCL(d01, w0.y); ACCL(d02, w0.z); ACCL(d03, w0.w);
            ACCL(d10, w1.x); ACCL(d11, w1.y); ACCL(d12, w1.z); ACCL(d13, w1.w);
            ACCL(d20, w2.x); ACCL(d21, w2.y); ACCL(d22, w2.z); ACCL(d23, w2.w);
            ACCL(d30, w3.x); ACCL(d31, w3.y); ACCL(d32, w3.z); ACCL(d33, w3.w);
        }
        // batch 2: 16 independent hi-half loads in flight
        {
            float4 d00 = LD(c00 + 16), d01 = LD(c01 + 16), d02 = LD(c02 + 16), d03 = LD(c03 + 16);
            float4 d10 = LD(c10 + 16), d11 = LD(c11 + 16), d12 = LD(c12 + 16), d13 = LD(c13 + 16);
            float4 d20 = LD(c20 + 16), d21 = LD(c21 + 16), d22 = LD(c22 + 16), d23 = LD(c23 + 16);
            float4 d30 = LD(c30 + 16), d31 = LD(c31 + 16), d32 = LD(c32 + 16), d33 = LD(c33 + 16);
            ACCH(d00, w0.x); ACCH(d01, w0.y); ACCH(d02, w0.z); ACCH(d03, w0.w);
            ACCH(d10, w1.x); ACCH(d11, w1.y); ACCH(d12, w1.z); ACCH(d13, w1.w);
            ACCH(d20, w2.x); ACCH(d21, w2.y); ACCH(d22, w2.z); ACCH(d23, w2.w);
            ACCH(d30, w3.x); ACCH(d31, w3.y); ACCH(d32, w3.z); ACCH(d33, w3.w);
        }
        #undef LD
        #undef ACCL
        #undef ACCH

        // reduce over ps (lane bits 2,3)
        #pragma unroll
        for (int m = 4; m <= 8; m <<= 1) {
            a0 += __shfl_xor(a0, m, 64); a1 += __shfl_xor(a1, m, 64);
            a2 += __shfl_xor(a2, m, 64); a3 += __shfl_xor(a3, m, 64);
            a4 += __shfl_xor(a4, m, 64); a5 += __shfl_xor(a5, m, 64);
            a6 += __shfl_xor(a6, m, 64); a7 += __shfl_xor(a7, m, 64);
        }

        int qg = q0 + q;
        if (ps == 0 && qg < NQ) {
            float* op = out + ((size_t)(b * NQ + qg)) * CDIM + h * 32;
            *reinterpret_cast<float4*>(op + cp4 * 4)      = make_float4(a0, a1, a2, a3);
            *reinterpret_cast<float4*>(op + 16 + cp4 * 4) = make_float4(a4, a5, a6, a7);
        }
    }
}

extern "C" void kernel_launch(void* const* d_in, const int* in_sizes, int n_in,
                              void* d_out, int out_size, void* d_ws, size_t ws_size,
                              hipStream_t stream) {
    const float* query  = (const float*)d_in[0];
    const float* refp   = (const float*)d_in[1];
    const float* value  = (const float*)d_in[2];
    const float* W_off  = (const float*)d_in[3];
    const float* b_off  = (const float*)d_in[4];
    const float* W_attn = (const float*)d_in[5];
    const float* b_attn = (const float*)d_in[6];
    float* out = (float*)d_out;

    msda_kernel<<<NBLK, 256, 0, stream>>>(query, refp, value, W_off, b_off,
                                          W_attn, b_attn, out);
}

// Round 14
// 140.049 us; speedup vs baseline: 1.5268x; 1.0162x over previous
//
#include <hip/hip_runtime.h>

#define NHEAD 8
#define NQ 300
#define NBS 32
#define VTOT 8500
#define CDIM 256
#define TQ 16
#define NQT 19  // ceil(300/16)
#define NBLK (NBS * NHEAD * NQT)  // 4864 = 8 XCDs x 608

typedef float f32x4 __attribute__((ext_vector_type(4)));

// Fully fused MSDA, direct fp32 gather; inline-asm 16-deep load batches.
__global__ __launch_bounds__(256, 2)
void msda_kernel(const float* __restrict__ query,
                 const float* __restrict__ refp,
                 const float* __restrict__ value,
                 const float* __restrict__ W_off,
                 const float* __restrict__ b_off,
                 const float* __restrict__ W_attn,
                 const float* __restrict__ b_attn,
                 float* __restrict__ out) {
    __shared__ float Aq[TQ * 260];        // aliased by Pid/Pw after phase 1
    __shared__ float S[TQ * 49];
    __shared__ float Rp[TQ * 4];

    int4*   Pid = reinterpret_cast<int4*>(Aq);            // 256 int4  = 4096 B
    float4* Pw  = reinterpret_cast<float4*>(Aq + 1024);   // 256 float4 = 4096 B

    const int tid = threadIdx.x;
    // Chunked XCD swizzle: pid%8 = XCD -> contiguous b-major chunk per XCD.
    const int pid = blockIdx.x;
    const int bid = (pid & 7) * (NBLK / 8) + (pid >> 3);
    const int b   = bid / (NHEAD * NQT);
    const int r_  = bid - b * (NHEAD * NQT);
    const int h   = r_ / NQT;
    const int qt  = r_ - h * NQT;
    const int q0  = qt * TQ;

    // ---- phase 0: stage query tile + reference points ----
    #pragma unroll
    for (int i = 0; i < 4; ++i) {
        int f4 = i * 256 + tid;
        int q  = f4 >> 6;
        int kk = (f4 & 63) << 2;
        float4 v = make_float4(0.f, 0.f, 0.f, 0.f);
        if (q0 + q < NQ)
            v = *reinterpret_cast<const float4*>(
                    query + ((size_t)(b * NQ + q0 + q) * CDIM + kk));
        *reinterpret_cast<float4*>(&Aq[q * 260 + kk]) = v;
    }
    if (tid < TQ * 4) {
        int q = tid >> 2, c = tid & 3;
        Rp[tid] = (q0 + q < NQ) ? refp[((size_t)(b * NQ + q0 + q)) * 4 + c] : 0.5f;
    }
    __syncthreads();

    // ---- phase 1: GEMM 16q x 48 outputs, thread = (q, 4-col group) ----
    if (tid < 192) {
        const int q = tid / 12;
        const int g = tid - q * 12;
        const float* Wp;
        const float* bp;
        int stride, colbase, j;
        if (g < 8) {
            Wp = W_off;  bp = b_off;  stride = 256;
            colbase = h * 32 + 4 * g;  j = 4 * g;
        } else {
            Wp = W_attn; bp = b_attn; stride = 128;
            colbase = h * 16 + 4 * (g - 8); j = 32 + 4 * (g - 8);
        }
        float4 acc = *reinterpret_cast<const float4*>(bp + colbase);
        const float* a    = &Aq[q * 260];
        const float* wrow = Wp + colbase;
        #pragma unroll 2
        for (int k = 0; k < CDIM; k += 4) {
            float4 av = *reinterpret_cast<const float4*>(a + k);
            float4 w0 = *reinterpret_cast<const float4*>(wrow + (size_t)(k + 0) * stride);
            float4 w1 = *reinterpret_cast<const float4*>(wrow + (size_t)(k + 1) * stride);
            float4 w2 = *reinterpret_cast<const float4*>(wrow + (size_t)(k + 2) * stride);
            float4 w3 = *reinterpret_cast<const float4*>(wrow + (size_t)(k + 3) * stride);
            acc.x = fmaf(av.x, w0.x, acc.x); acc.y = fmaf(av.x, w0.y, acc.y);
            acc.z = fmaf(av.x, w0.z, acc.z); acc.w = fmaf(av.x, w0.w, acc.w);
            acc.x = fmaf(av.y, w1.x, acc.x); acc.y = fmaf(av.y, w1.y, acc.y);
            acc.z = fmaf(av.y, w1.z, acc.z); acc.w = fmaf(av.y, w1.w, acc.w);
            acc.x = fmaf(av.z, w2.x, acc.x); acc.y = fmaf(av.z, w2.y, acc.y);
            acc.z = fmaf(av.z, w2.z, acc.z); acc.w = fmaf(av.z, w2.w, acc.w);
            acc.x = fmaf(av.w, w3.x, acc.x); acc.y = fmaf(av.w, w3.y, acc.y);
            acc.z = fmaf(av.w, w3.z, acc.z); acc.w = fmaf(av.w, w3.w, acc.w);
        }
        S[q * 49 + j + 0] = acc.x;
        S[q * 49 + j + 1] = acc.y;
        S[q * 49 + j + 2] = acc.z;
        S[q * 49 + j + 3] = acc.w;
    }
    __syncthreads();

    // ---- phase 2: softmax + location + corner idx / premultiplied weights ----
    {
        const int q = tid >> 4;
        const int p = tid & 15;
        const float* Sq = &S[q * 49];

        float m = Sq[32];
        #pragma unroll
        for (int jj = 1; jj < 16; ++jj) m = fmaxf(m, Sq[32 + jj]);
        float ssum = 0.f;
        #pragma unroll
        for (int jj = 0; jj < 16; ++jj) ssum += __expf(Sq[32 + jj] - m);
        float aw = __expf(Sq[32 + p] - m) / ssum;

        float offx = Sq[2 * p], offy = Sq[2 * p + 1];
        float rx = Rp[q * 4 + 0], ry = Rp[q * 4 + 1];
        float rw = Rp[q * 4 + 2], rh = Rp[q * 4 + 3];
        float locx = rx + offx * 0.25f * rw * 0.5f;
        float locy = ry + offy * 0.25f * rh * 0.5f;

        int l  = p >> 2;
        int Wl = 80 >> l;
        int Hl = Wl;
        int base = (l > 0 ? 6400 : 0) + (l > 1 ? 1600 : 0) + (l > 2 ? 400 : 0);

        float x = locx * (float)Wl - 0.5f;
        float y = locy * (float)Hl - 0.5f;
        float x0f = floorf(x), y0f = floorf(y);
        float lx = x - x0f, ly = y - y0f;
        int x0 = (int)x0f, y0 = (int)y0f;
        int x1 = x0 + 1,   y1 = y0 + 1;

        bool vx0 = (x0 >= 0) && (x0 < Wl);
        bool vx1 = (x1 >= 0) && (x1 < Wl);
        bool vy0 = (y0 >= 0) && (y0 < Hl);
        bool vy1 = (y1 >= 0) && (y1 < Hl);
        int cx0 = min(max(x0, 0), Wl - 1), cx1 = min(max(x1, 0), Wl - 1);
        int cy0 = min(max(y0, 0), Hl - 1), cy1 = min(max(y1, 0), Hl - 1);

        float wx0 = 1.f - lx, wy0 = 1.f - ly;
        float w00 = wx0 * wy0 * aw * (float)(vx0 && vy0);
        float w10 = lx  * wy0 * aw * (float)(vx1 && vy0);
        float w01 = wx0 * ly  * aw * (float)(vx0 && vy1);
        float w11 = lx  * ly  * aw * (float)(vx1 && vy1);

        int s = (p + q) & 15;  // bank swizzle (matched by phase 3)
        Pid[q * 16 + s] = make_int4(base + cy0 * Wl + cx0, base + cy0 * Wl + cx1,
                                    base + cy1 * Wl + cx0, base + cy1 * Wl + cx1);
        Pw[q * 16 + s]  = make_float4(w00, w10, w01, w11);
    }
    __syncthreads();

    // ---- phase 3: fp32 gathers, inline-asm 16-deep in-flight batches ----
    {
        const int cp4 = tid & 3;          // 16B quad within the 64B half-slice
        const int ps  = (tid >> 2) & 3;   // 4-way p-split
        const int q   = tid >> 4;         // 16 q
        const float* vbase = value + (size_t)b * VTOT * CDIM + h * 32 + cp4 * 4;

        int4   id0, id1, id2, id3;
        float4 w0, w1, w2, w3;
        { int s = (ps + 0  + q) & 15; id0 = Pid[q * 16 + s]; w0 = Pw[q * 16 + s]; }
        { int s = (ps + 4  + q) & 15; id1 = Pid[q * 16 + s]; w1 = Pw[q * 16 + s]; }
        { int s = (ps + 8  + q) & 15; id2 = Pid[q * 16 + s]; w2 = Pw[q * 16 + s]; }
        { int s = (ps + 12 + q) & 15; id3 = Pid[q * 16 + s]; w3 = Pw[q * 16 + s]; }

        const float* c00 = vbase + (size_t)id0.x * CDIM;
        const float* c01 = vbase + (size_t)id0.y * CDIM;
        const float* c02 = vbase + (size_t)id0.z * CDIM;
        const float* c03 = vbase + (size_t)id0.w * CDIM;
        const float* c10 = vbase + (size_t)id1.x * CDIM;
        const float* c11 = vbase + (size_t)id1.y * CDIM;
        const float* c12 = vbase + (size_t)id1.z * CDIM;
        const float* c13 = vbase + (size_t)id1.w * CDIM;
        const float* c20 = vbase + (size_t)id2.x * CDIM;
        const float* c21 = vbase + (size_t)id2.y * CDIM;
        const float* c22 = vbase + (size_t)id2.z * CDIM;
        const float* c23 = vbase + (size_t)id2.w * CDIM;
        const float* c30 = vbase + (size_t)id3.x * CDIM;
        const float* c31 = vbase + (size_t)id3.y * CDIM;
        const float* c32 = vbase + (size_t)id3.z * CDIM;
        const float* c33 = vbase + (size_t)id3.w * CDIM;

        float a0 = 0.f, a1 = 0.f, a2 = 0.f, a3 = 0.f;
        float a4 = 0.f, a5 = 0.f, a6 = 0.f, a7 = 0.f;

        f32x4 d00, d01, d02, d03, d10, d11, d12, d13;
        f32x4 d20, d21, d22, d23, d30, d31, d32, d33;

        #define GLD(dst, addr) \
            asm volatile("global_load_dwordx4 %0, %1, off" : "=&v"(dst) : "v"(addr))
        #define FENCE() \
            asm volatile("s_waitcnt vmcnt(0)" ::: "memory"); \
            __builtin_amdgcn_sched_barrier(0)
        #define ACCL(dv, wv) { a0 = fmaf(wv, dv.x, a0); a1 = fmaf(wv, dv.y, a1); \
                               a2 = fmaf(wv, dv.z, a2); a3 = fmaf(wv, dv.w, a3); }
        #define ACCH(dv, wv) { a4 = fmaf(wv, dv.x, a4); a5 = fmaf(wv, dv.y, a5); \
                               a6 = fmaf(wv, dv.z, a6); a7 = fmaf(wv, dv.w, a7); }

        // batch 1: 16 lo-half loads pinned in flight
        GLD(d00, c00); GLD(d01, c01); GLD(d02, c02); GLD(d03, c03);
        GLD(d10, c10); GLD(d11, c11); GLD(d12, c12); GLD(d13, c13);
        GLD(d20, c20); GLD(d21, c21); GLD(d22, c22); GLD(d23, c23);
        GLD(d30, c30); GLD(d31, c31); GLD(d32, c32); GLD(d33, c33);
        FENCE();
        ACCL(d00, w0.x); ACCL(d01, w0.y); ACCL(d02, w0.z); ACCL(d03, w0.w);
        ACCL(d10, w1.x); ACCL(d11, w1.y); ACCL(d12, w1.z); ACCL(d13, w1.w);
        ACCL(d20, w2.x); ACCL(d21, w2.y); ACCL(d22, w2.z); ACCL(d23, w2.w);
        ACCL(d30, w3.x); ACCL(d31, w3.y); ACCL(d32, w3.z); ACCL(d33, w3.w);

        // batch 2: 16 hi-half loads pinned in flight
        GLD(d00, c00 + 16); GLD(d01, c01 + 16); GLD(d02, c02 + 16); GLD(d03, c03 + 16);
        GLD(d10, c10 + 16); GLD(d11, c11 + 16); GLD(d12, c12 + 16); GLD(d13, c13 + 16);
        GLD(d20, c20 + 16); GLD(d21, c21 + 16); GLD(d22, c22 + 16); GLD(d23, c23 + 16);
        GLD(d30, c30 + 16); GLD(d31, c31 + 16); GLD(d32, c32 + 16); GLD(d33, c33 + 16);
        FENCE();
        ACCH(d00, w0.x); ACCH(d01, w0.y); ACCH(d02, w0.z); ACCH(d03, w0.w);
        ACCH(d10, w1.x); ACCH(d11, w1.y); ACCH(d12, w1.z); ACCH(d13, w1.w);
        ACCH(d20, w2.x); ACCH(d21, w2.y); ACCH(d22, w2.z); ACCH(d23, w2.w);
        ACCH(d30, w3.x); ACCH(d31, w3.y); ACCH(d32, w3.z); ACCH(d33, w3.w);

        #undef GLD
        #undef FENCE
        #undef ACCL
        #undef ACCH

        // reduce over ps (lane bits 2,3)
        #pragma unroll
        for (int m = 4; m <= 8; m <<= 1) {
            a0 += __shfl_xor(a0, m, 64); a1 += __shfl_xor(a1, m, 64);
            a2 += __shfl_xor(a2, m, 64); a3 += __shfl_xor(a3, m, 64);
            a4 += __shfl_xor(a4, m, 64); a5 += __shfl_xor(a5, m, 64);
            a6 += __shfl_xor(a6, m, 64); a7 += __shfl_xor(a7, m, 64);
        }

        int qg = q0 + q;
        if (ps == 0 && qg < NQ) {
            float* op = out + ((size_t)(b * NQ + qg)) * CDIM + h * 32;
            *reinterpret_cast<float4*>(op + cp4 * 4)      = make_float4(a0, a1, a2, a3);
            *reinterpret_cast<float4*>(op + 16 + cp4 * 4) = make_float4(a4, a5, a6, a7);
        }
    }
}

extern "C" void kernel_launch(void* const* d_in, const int* in_sizes, int n_in,
                              void* d_out, int out_size, void* d_ws, size_t ws_size,
                              hipStream_t stream) {
    const float* query  = (const float*)d_in[0];
    const float* refp   = (const float*)d_in[1];
    const float* value  = (const float*)d_in[2];
    const float* W_off  = (const float*)d_in[3];
    const float* b_off  = (const float*)d_in[4];
    const float* W_attn = (const float*)d_in[5];
    const float* b_attn = (const float*)d_in[6];
    float* out = (float*)d_out;

    msda_kernel<<<NBLK, 256, 0, stream>>>(query, refp, value, W_off, b_off,
                                          W_attn, b_attn, out);
}